// Round 12
// baseline (244.263 us; speedup 1.0000x reference)
//
#include <hip/hip_runtime.h>

typedef unsigned short u16;
typedef unsigned int   u32;

using bf16x8 = __attribute__((ext_vector_type(8))) short;
using f32x4  = __attribute__((ext_vector_type(4))) float;

#define MFMA16(a, b, c) __builtin_amdgcn_mfma_f32_16x16x32_bf16((a), (b), (c), 0, 0, 0)

__device__ __forceinline__ u16 f2bf(float f) {
  union { float f; u32 u; } x; x.f = f;
  u32 r = x.u + 0x7fffu + ((x.u >> 16) & 1u);
  return (u16)(r >> 16);
}

__device__ __forceinline__ float bf2f(u16 v) {
  union { u32 u; float f; } x; x.u = ((u32)v) << 16;
  return x.f;
}

// packed f32x2 -> bf16x2 (RNE), single instruction; no builtin on gfx950
__device__ __forceinline__ u32 cvtpk(float lo, float hi) {
  u32 r;
  asm("v_cvt_pk_bf16_f32 %0, %1, %2" : "=v"(r) : "v"(lo), "v"(hi));
  return r;
}

// async global->LDS, 16B per lane; LDS dest must be wave-uniform base (HW adds lane*16)
__device__ __forceinline__ void gl2lds16(const void* g, void* l) {
  __builtin_amdgcn_global_load_lds(
      (const __attribute__((address_space(1))) u32*)g,
      (__attribute__((address_space(3))) u32*)l, 16, 0, 0);
}

// ---------------- weight convert + transpose: W[K][N] f32 -> Wt[N][K] bf16 --
__global__ __launch_bounds__(256) void wt_cvt_t(const float* __restrict__ W,
                                                u16* __restrict__ Wt, int K, int N) {
  __shared__ u16 t[64][66];
  int tilesN = N >> 6;
  int k0 = ((int)blockIdx.x / tilesN) << 6;
  int n0 = ((int)blockIdx.x % tilesN) << 6;
  int tid = threadIdx.x;
  int c4 = (tid & 15) * 4, r16 = tid >> 4;
#pragma unroll
  for (int p = 0; p < 4; ++p) {
    int row = r16 + p * 16;
    float4 f = *(const float4*)(W + (size_t)(k0 + row) * N + n0 + c4);
    t[row][c4 + 0] = f2bf(f.x);
    t[row][c4 + 1] = f2bf(f.y);
    t[row][c4 + 2] = f2bf(f.z);
    t[row][c4 + 3] = f2bf(f.w);
  }
  __syncthreads();
  int c8 = (tid & 7) * 8, r32 = tid >> 3;
#pragma unroll
  for (int p = 0; p < 2; ++p) {
    int n = r32 + p * 32;
    u16 tmp[8] __attribute__((aligned(16)));
#pragma unroll
    for (int e = 0; e < 8; ++e) tmp[e] = t[c8 + e][n];
    *(uint4*)(Wt + (size_t)(n0 + n) * K + k0 + c8) = *(uint4*)tmp;
  }
}

// ---------------- MFMA GEMM: C[M][N] = A[M][K] * Bt[N][K]^T + bias ---------
// R11 core: 128x128 tile, BK=64, 8 waves (2m x 4n, 64x32/wave), XOR-swizzled
// LDS, double-buffered counted-vmcnt pipeline, swapped-operand MFMA with
// packed epilogue.
// AF32=true (v/s-proj): A is f32; conversion FUSED into staging via T14
//   issue-early/write-late: regs for tile kt+1 issued at iter kt-1 (full
//   iteration of HBM latency), cvt_pk + swizzled ds_write at iter kt.
//   vmcnt ledger (order per iter: [Af32(kt+2), B(kt+1)]):
//     top of iter kt: outstanding = Af32(kt+1)[4] + B(kt)[2]
//     vmcnt(2) -> Af32(kt+1) regs ready; cvt+ds_write; issue Af32(kt+2),
//     stage B(kt+1) -> vmcnt(6) retires exactly B(kt); BAR; COMPUTE;
//     lgkm(0) (publish my ds_writes); BAR.
// AF32=false: R11 gl2lds path unchanged.
// MODE 0: relu, write bf16 (8B stores)
// MODE 2: write bf16 permuted to [B][H][L][64]
// MODE 4: like 2, plus transposed write [BH][64][512]
// MODE 3: out = acc + bias + bf2f(add0b) + add1, f32 (16B ld/st)
template <int MODE, bool AF32>
__global__ __launch_bounds__(512) void gemm_bf16(
    const void* __restrict__ Av, const u16* __restrict__ Bt,
    const float* __restrict__ bias, u16* __restrict__ outb, float* __restrict__ outf,
    u16* __restrict__ outt, const u16* __restrict__ add0b,
    const float* __restrict__ add1, int M, int N, int K) {
  __shared__ u16 sA[2][128 * 64];
  __shared__ u16 sB[2][128 * 64];
  int tilesN = N >> 7;
  // bijective XCD-chunked swizzle: XCD x owns a contiguous tm range (A stays L2-hot)
  int nwg = (int)gridDim.x;
  int cpx = nwg >> 3;
  int orig = (int)blockIdx.x;
  int wg = (orig & 7) * cpx + (orig >> 3);
  int tm = wg / tilesN, tn = wg % tilesN;
  int m0 = tm << 7, n0 = tn << 7;
  int tid = threadIdx.x, w = tid >> 6, l = tid & 63;
  int wm = (w >> 2) << 6, wn = (w & 3) << 5;
  int c16 = l & 15, hi = l >> 4, g16 = hi * 16;

  f32x4 acc[4][2];
#pragma unroll
  for (int i = 0; i < 4; ++i)
#pragma unroll
    for (int j = 0; j < 2; ++j) acc[i][j] = (f32x4){0.f, 0.f, 0.f, 0.f};

  auto COMPUTE = [&](int buf) {
#pragma unroll
    for (int kk = 0; kk < 2; ++kk) {
      bf16x8 af[4], bfr[2];
#pragma unroll
      for (int i = 0; i < 4; ++i) {
        int ar = wm + i * 16 + c16;
        af[i] = *(const bf16x8*)((const char*)sA[buf] + ar * 128 +
                                 ((kk * 64 + g16) ^ ((ar & 7) << 4)));
      }
#pragma unroll
      for (int j = 0; j < 2; ++j) {
        int br = wn + j * 16 + c16;
        bfr[j] = *(const bf16x8*)((const char*)sB[buf] + br * 128 +
                                  ((kk * 64 + g16) ^ ((br & 7) << 4)));
      }
      // swapped operands: lane m = c16, n-quad = hi*4+r
#pragma unroll
      for (int i = 0; i < 4; ++i)
#pragma unroll
        for (int j = 0; j < 2; ++j) acc[i][j] = MFMA16(bfr[j], af[i], acc[i][j]);
    }
  };

  int nk = K >> 6;

  if constexpr (!AF32) {
    const u16* A = (const u16*)Av;
    auto STAGE = [&](int kt, int buf) {
      const u16* Ab = A + (size_t)m0 * K + kt * 64;
      const u16* Bb = Bt + (size_t)n0 * K + kt * 64;
#pragma unroll
      for (int p = 0; p < 2; ++p) {
        int lin = p * 8192 + tid * 16;
        int row = lin >> 7;
        int cb = (lin & 127) ^ ((row & 7) << 4);
        int base = lin & ~1023;
        gl2lds16(Ab + (size_t)row * K + (cb >> 1), (char*)sA[buf] + base);
        gl2lds16(Bb + (size_t)row * K + (cb >> 1), (char*)sB[buf] + base);
      }
    };
    STAGE(0, 0);
    int cur = 0;
    for (int kt = 0; kt < nk; ++kt) {
      if (kt + 1 < nk) {
        STAGE(kt + 1, cur ^ 1);
        __builtin_amdgcn_sched_barrier(0);
        asm volatile("s_waitcnt vmcnt(4)" ::: "memory");
      } else {
        asm volatile("s_waitcnt vmcnt(0)" ::: "memory");
      }
      __builtin_amdgcn_s_barrier();
      __builtin_amdgcn_sched_barrier(0);
      COMPUTE(cur);
      __builtin_amdgcn_sched_barrier(0);
      __builtin_amdgcn_s_barrier();
      cur ^= 1;
    }
  } else {
    const float* Af = (const float*)Av;
    // per-thread A unit: row = tid>>2 (0..127), 32 bf16 bytes at acol
    int arow = tid >> 2;
    int acol = (tid & 3) * 32;            // byte col within 128B bf16 row
    int aswz = (arow & 7) << 4;
    float4 fr0, fr1, fr2, fr3;            // f32 staging regs (one tile unit)
    auto AF_ISSUE = [&](int kt) {
      const float* s = Af + (size_t)(m0 + arow) * K + kt * 64 + (acol >> 1);
      fr0 = *(const float4*)(s + 0);
      fr1 = *(const float4*)(s + 4);
      fr2 = *(const float4*)(s + 8);
      fr3 = *(const float4*)(s + 12);
    };
    auto AF_WRITE = [&](int buf) {
      uint4 w0, w1;
      w0.x = cvtpk(fr0.x, fr0.y); w0.y = cvtpk(fr0.z, fr0.w);
      w0.z = cvtpk(fr1.x, fr1.y); w0.w = cvtpk(fr1.z, fr1.w);
      w1.x = cvtpk(fr2.x, fr2.y); w1.y = cvtpk(fr2.z, fr2.w);
      w1.z = cvtpk(fr3.x, fr3.y); w1.w = cvtpk(fr3.z, fr3.w);
      char* base = (char*)sA[buf] + arow * 128;
      *(uint4*)(base + (acol ^ aswz)) = w0;
      *(uint4*)(base + ((acol + 16) ^ aswz)) = w1;
    };
    auto STAGE_B = [&](int kt, int buf) {
      const u16* Bb = Bt + (size_t)n0 * K + kt * 64;
#pragma unroll
      for (int p = 0; p < 2; ++p) {
        int lin = p * 8192 + tid * 16;
        int row = lin >> 7;
        int cb = (lin & 127) ^ ((row & 7) << 4);
        gl2lds16(Bb + (size_t)row * K + (cb >> 1), (char*)sB[buf] + (lin & ~1023));
      }
    };

    // prologue: cold-convert tile 0, then establish steady outstanding
    // pattern [Af32(1) x4, B(0) x2]
    AF_ISSUE(0);
    asm volatile("s_waitcnt vmcnt(0)" ::: "memory");
    AF_WRITE(0);
    AF_ISSUE(1);
    STAGE_B(0, 0);
    __builtin_amdgcn_sched_barrier(0);
    asm volatile("s_waitcnt lgkmcnt(0)" ::: "memory");
    __builtin_amdgcn_s_barrier();

    int cur = 0;
    for (int kt = 0; kt < nk; ++kt) {
      if (kt + 1 < nk) {
        // Af32(kt+1) regs ready (leaves B(kt) in flight)
        asm volatile("s_waitcnt vmcnt(2)" ::: "memory");
        __builtin_amdgcn_sched_barrier(0);
        AF_WRITE(cur ^ 1);                 // bf16 tile kt+1 into back buffer
        if (kt + 2 < nk) AF_ISSUE(kt + 2); // refill staging regs
        STAGE_B(kt + 1, cur ^ 1);
        __builtin_amdgcn_sched_barrier(0);
        if (kt + 2 < nk)
          asm volatile("s_waitcnt vmcnt(6)" ::: "memory");  // retires B(kt)
        else
          asm volatile("s_waitcnt vmcnt(2)" ::: "memory");  // retires B(kt)
      } else {
        asm volatile("s_waitcnt vmcnt(0)" ::: "memory");
      }
      __builtin_amdgcn_s_barrier();        // buf[cur] (A ds_write'd last iter,
      __builtin_amdgcn_sched_barrier(0);   //  B gl2lds'd) published
      COMPUTE(cur);
      __builtin_amdgcn_sched_barrier(0);
      asm volatile("s_waitcnt lgkmcnt(0)" ::: "memory");  // my A ds_writes done
      __builtin_amdgcn_s_barrier();        // all waves done with buf[cur]
      cur ^= 1;
    }
  }

  // ---- packed epilogue (regs span 4 consecutive n) ----
#pragma unroll
  for (int i = 0; i < 4; ++i) {
    int gm = m0 + wm + i * 16 + c16;
#pragma unroll
    for (int j = 0; j < 2; ++j) {
      int gn0 = n0 + wn + j * 16 + hi * 4;
      float4 b4 = *(const float4*)(bias + gn0);
      float vv[4];
      vv[0] = acc[i][j][0] + b4.x;
      vv[1] = acc[i][j][1] + b4.y;
      vv[2] = acc[i][j][2] + b4.z;
      vv[3] = acc[i][j][3] + b4.w;
      if (MODE == 0) {
#pragma unroll
        for (int r = 0; r < 4; ++r) vv[r] = fmaxf(vv[r], 0.f);
        uint2 pw;
        pw.x = cvtpk(vv[0], vv[1]);
        pw.y = cvtpk(vv[2], vv[3]);
        *(uint2*)(outb + (size_t)gm * N + gn0) = pw;
      } else if (MODE == 2 || MODE == 4) {
        int hh = gn0 >> 6, dk0 = gn0 & 63, bb2 = gm >> 9, ll2 = gm & 511;
        uint2 pw;
        pw.x = cvtpk(vv[0], vv[1]);
        pw.y = cvtpk(vv[2], vv[3]);
        *(uint2*)(outb + (((size_t)bb2 * 16 + hh) * 512 + ll2) * 64 + dk0) = pw;
        if (MODE == 4) {
          u16* tb = outt + ((size_t)bb2 * 16 + hh) * 32768 + ll2;
#pragma unroll
          for (int r = 0; r < 4; ++r) tb[(size_t)(dk0 + r) * 512] = f2bf(vv[r]);
        }
      } else {  // MODE 3
        uint2 a0 = *(const uint2*)(add0b + (size_t)gm * N + gn0);
        float4 a1 = *(const float4*)(add1 + (size_t)(gm & 511) * N + gn0);
        float4 o;
        o.x = vv[0] + bf2f((u16)(a0.x & 0xffff)) + a1.x;
        o.y = vv[1] + bf2f((u16)(a0.x >> 16)) + a1.y;
        o.z = vv[2] + bf2f((u16)(a0.y & 0xffff)) + a1.z;
        o.w = vv[3] + bf2f((u16)(a0.y >> 16)) + a1.w;
        *(float4*)(outf + (size_t)gm * N + gn0) = o;
      }
    }
  }
}

// ---------------- fused attention: swapped-QK^T + swapped-PV ---------------
__global__ __launch_bounds__(512) void attn_kernel(const u16* __restrict__ q,
                                                   const u16* __restrict__ kv,
                                                   const u16* __restrict__ kvT,
                                                   u16* __restrict__ ctx) {
  __shared__ u16 sK[2][4096];   // [64 keys][64 dk], 128B rows, XOR swizzle
  __shared__ u16 sVT[2][4096];  // [64 dv][64 keys]
  __shared__ u16 sP[8192];      // Q staging (128x64), then per-wave P (16x64 each)

  int orig = (int)blockIdx.x;
  int r = (orig & 7) * 128 + (orig >> 3);
  int bh = r >> 2, qt = r & 3;
  int b = bh >> 4, h = bh & 15;
  int tid = threadIdx.x, w = tid >> 6, l = tid & 63;
  int c16 = l & 15, hi = l >> 4, g16 = hi * 16;
  int swzq = (c16 & 7) << 4;

  const u16* qbase = q + (size_t)bh * 32768 + (size_t)qt * 8192;
#pragma unroll
  for (int j = 0; j < 2; ++j) {
    int chunk = w * 2 + j;
    int lin = chunk * 1024 + l * 16;
    int row = lin >> 7;
    int cb = (lin & 127) ^ ((row & 7) << 4);
    gl2lds16(qbase + (size_t)row * 64 + (cb >> 1), (char*)sP + chunk * 1024);
  }
  {
    const u16* kb = kv + (size_t)bh * 32768;
    const u16* vb = kvT + (size_t)bh * 32768;
    int lin = w * 1024 + l * 16;
    int row = lin >> 7;
    int cb = (lin & 127) ^ ((row & 7) << 4);
    gl2lds16(kb + (size_t)row * 64 + (cb >> 1), (char*)sK[0] + w * 1024);
    gl2lds16(vb + (size_t)row * 512 + (cb >> 1), (char*)sVT[0] + w * 1024);
  }
  __syncthreads();

  const char* sQrow = (const char*)sP + (w * 16 + c16) * 128;
  bf16x8 qf0 = *(const bf16x8*)(sQrow + ((0 + g16) ^ swzq));
  bf16x8 qf1 = *(const bf16x8*)(sQrow + ((64 + g16) ^ swzq));

  char* sPw = (char*)sP + w * 2048;
  f32x4 of[4];
#pragma unroll
  for (int n = 0; n < 4; ++n) of[n] = (f32x4){0.f, 0.f, 0.f, 0.f};
  float m_run = -1e30f, l_run = 0.f;

  for (int c = 0; c < 8; ++c) {
    int cur = c & 1;
    if (c < 7) {
      const u16* kb = kv + (size_t)bh * 32768 + (size_t)(c + 1) * 4096;
      const u16* vb = kvT + (size_t)bh * 32768 + (c + 1) * 64;
      int lin = w * 1024 + l * 16;
      int row = lin >> 7;
      int cb = (lin & 127) ^ ((row & 7) << 4);
      gl2lds16(kb + (size_t)row * 64 + (cb >> 1), (char*)sK[cur ^ 1] + w * 1024);
      gl2lds16(vb + (size_t)row * 512 + (cb >> 1), (char*)sVT[cur ^ 1] + w * 1024);
    }
    const char* kbuf = (const char*)sK[cur];
    const char* vtbuf = (const char*)sVT[cur];

    f32x4 sf[4];
#pragma unroll
    for (int n = 0; n < 4; ++n) {
      const char* krow = kbuf + (n * 16 + c16) * 128;
      bf16x8 k0 = *(const bf16x8*)(krow + (g16 ^ swzq));
      bf16x8 k1 = *(const bf16x8*)(krow + ((64 + g16) ^ swzq));
      f32x4 z = (f32x4){0.f, 0.f, 0.f, 0.f};
      z = MFMA16(k0, qf0, z);
      z = MFMA16(k1, qf1, z);
      sf[n] = z;
    }

    float pmax = -1e30f;
#pragma unroll
    for (int n = 0; n < 4; ++n)
#pragma unroll
      for (int rr = 0; rr < 4; ++rr) {
        sf[n][rr] *= 0.125f;
        pmax = fmaxf(pmax, sf[n][rr]);
      }
    pmax = fmaxf(pmax, __shfl_xor(pmax, 16));
    pmax = fmaxf(pmax, __shfl_xor(pmax, 32));
    float mnew = fmaxf(m_run, pmax);
    float corr = __expf(m_run - mnew);
    float psum = 0.f;
#pragma unroll
    for (int n = 0; n < 4; ++n)
#pragma unroll
      for (int rr = 0; rr < 4; ++rr) {
        float p = __expf(sf[n][rr] - mnew);
        sf[n][rr] = p;
        psum += p;
      }
    psum += __shfl_xor(psum, 16);
    psum += __shfl_xor(psum, 32);
    l_run = l_run * corr + psum;
    m_run = mnew;
#pragma unroll
    for (int n = 0; n < 4; ++n)
#pragma unroll
      for (int rr = 0; rr < 4; ++rr) of[n][rr] *= corr;

#pragma unroll
    for (int n = 0; n < 4; ++n) {
      uint2 pw;
      pw.x = cvtpk(sf[n][0], sf[n][1]);
      pw.y = cvtpk(sf[n][2], sf[n][3]);
      *(uint2*)(sPw + c16 * 128 + ((n * 32 + hi * 8) ^ swzq)) = pw;
    }

    bf16x8 pf0 = *(const bf16x8*)(sPw + c16 * 128 + (g16 ^ swzq));
    bf16x8 pf1 = *(const bf16x8*)(sPw + c16 * 128 + ((64 + g16) ^ swzq));
#pragma unroll
    for (int n = 0; n < 4; ++n) {
      const char* vrow = vtbuf + (n * 16 + c16) * 128;
      bf16x8 v0 = *(const bf16x8*)(vrow + (g16 ^ swzq));
      bf16x8 v1 = *(const bf16x8*)(vrow + ((64 + g16) ^ swzq));
      of[n] = MFMA16(v0, pf0, of[n]);
      of[n] = MFMA16(v1, pf1, of[n]);
    }
    __syncthreads();
  }

  float inv = 1.0f / l_run;
  int grow = qt * 128 + w * 16 + c16;
  u16* obase = ctx + (size_t)(b * 512 + grow) * 1024 + h * 64;
#pragma unroll
  for (int n = 0; n < 4; ++n) {
    uint2 ow;
    ow.x = cvtpk(of[n][0] * inv, of[n][1] * inv);
    ow.y = cvtpk(of[n][2] * inv, of[n][3] * inv);
    *(uint2*)(obase + n * 16 + hi * 4) = ow;
  }
}

// ---------------- in-place LayerNorm over D=1024 ---------------------------
__global__ __launch_bounds__(256) void ln_kernel(float* __restrict__ x,
                                                 const float* __restrict__ gamma,
                                                 const float* __restrict__ beta) {
  __shared__ float red[4];
  __shared__ float red2[4];
  int row = blockIdx.x, tid = threadIdx.x;
  float4 v = *(float4*)(x + (size_t)row * 1024 + tid * 4);
  float s = v.x + v.y + v.z + v.w;
#pragma unroll
  for (int d = 1; d < 64; d <<= 1) s += __shfl_xor(s, d);
  if ((tid & 63) == 0) red[tid >> 6] = s;
  __syncthreads();
  float mu = (red[0] + red[1] + red[2] + red[3]) * (1.0f / 1024.0f);
  float d0 = v.x - mu, d1 = v.y - mu, d2 = v.z - mu, d3 = v.w - mu;
  float qq = d0 * d0 + d1 * d1 + d2 * d2 + d3 * d3;
#pragma unroll
  for (int d = 1; d < 64; d <<= 1) qq += __shfl_xor(qq, d);
  if ((tid & 63) == 0) red2[tid >> 6] = qq;
  __syncthreads();
  float var = (red2[0] + red2[1] + red2[2] + red2[3]) * (1.0f / 1024.0f);
  float rstd = rsqrtf(var + 1e-6f);
  float4 g = *(const float4*)(gamma + tid * 4);
  float4 bb = *(const float4*)(beta + tid * 4);
  v.x = g.x * d0 * rstd + bb.x;
  v.y = g.y * d1 * rstd + bb.y;
  v.z = g.z * d2 * rstd + bb.z;
  v.w = g.w * d3 * rstd + bb.w;
  *(float4*)(x + (size_t)row * 1024 + tid * 4) = v;
}

extern "C" void kernel_launch(void* const* d_in, const int* in_sizes, int n_in,
                              void* d_out, int out_size, void* d_ws, size_t ws_size,
                              hipStream_t stream) {
  (void)in_sizes; (void)n_in; (void)out_size; (void)ws_size;
  const float* v_in  = (const float*)d_in[0];
  const float* s_in  = (const float*)d_in[1];
  const float* W_lv  = (const float*)d_in[2];
  const float* b_lv  = (const float*)d_in[3];
  const float* W_ls  = (const float*)d_in[4];
  const float* b_ls  = (const float*)d_in[5];
  const float* pos_v = (const float*)d_in[6];
  // d_in[7] = pos_s (unused), d_in[10]/[11] = W_k/b_k (discarded in ref)
  const float* W_q   = (const float*)d_in[8];
  const float* b_q   = (const float*)d_in[9];
  const float* W_v   = (const float*)d_in[12];
  const float* b_v   = (const float*)d_in[13];
  const float* W_p   = (const float*)d_in[14];
  const float* b_p   = (const float*)d_in[15];
  const float* gamma = (const float*)d_in[16];
  const float* beta  = (const float*)d_in[17];
  float* out = (float*)d_out;

  char* ws = (char*)d_ws;
  size_t off = 0;
  auto alloc = [&](size_t bytes) {
    char* p = ws + off;
    off += (bytes + 255) & ~(size_t)255;
    return p;
  };
  u16* Wlv_t    = (u16*)alloc(4194304);    // [1024][2048] bf16
  u16* Wls_t    = (u16*)alloc(1572864);    // [1024][768]
  u16* Wq_t     = (u16*)alloc(2097152);    // [1024][1024]
  u16* Wv_t     = (u16*)alloc(2097152);
  u16* Wp_t     = (u16*)alloc(2097152);
  u16* vproj_bf = (u16*)alloc(16777216);   // [8192][1024] (also the residual, bf16)
  u16* sproj_bf = (u16*)alloc(16777216);
  u16* q_bf     = (u16*)alloc(16777216);   // [BH][512][64]
  u16* vs_bf    = (u16*)alloc(16777216);   // [BH][512][64]
  u16* vsT_bf   = (u16*)alloc(16777216);   // [BH][64][512]
  u16* ctx_bf   = (u16*)alloc(16777216);   // [8192][1024]

  wt_cvt_t<<<512, 256, 0, stream>>>(W_lv, Wlv_t, 2048, 1024);
  wt_cvt_t<<<192, 256, 0, stream>>>(W_ls, Wls_t, 768, 1024);
  wt_cvt_t<<<256, 256, 0, stream>>>(W_q, Wq_t, 1024, 1024);
  wt_cvt_t<<<256, 256, 0, stream>>>(W_v, Wv_t, 1024, 1024);
  wt_cvt_t<<<256, 256, 0, stream>>>(W_p, Wp_t, 1024, 1024);

  // v-proj + s-proj: fused f32->bf16 A-staging (T14 issue-early/write-late)
  gemm_bf16<0, true><<<512, 512, 0, stream>>>(v_in, Wlv_t, b_lv, vproj_bf, nullptr,
                                              nullptr, nullptr, nullptr, 8192, 1024, 2048);
  gemm_bf16<0, true><<<512, 512, 0, stream>>>(s_in, Wls_t, b_ls, sproj_bf, nullptr,
                                              nullptr, nullptr, nullptr, 8192, 1024, 768);
  // q-proj / vs-proj / out-proj: bf16 A via gl2lds (R11 proven path)
  gemm_bf16<2, false><<<512, 512, 0, stream>>>(vproj_bf, Wq_t, b_q, q_bf, nullptr,
                                               nullptr, nullptr, nullptr, 8192, 1024, 1024);
  gemm_bf16<4, false><<<512, 512, 0, stream>>>(sproj_bf, Wv_t, b_v, vs_bf, nullptr,
                                               vsT_bf, nullptr, nullptr, 8192, 1024, 1024);
  attn_kernel<<<1024, 512, 0, stream>>>(q_bf, vs_bf, vsT_bf, ctx_bf);
  gemm_bf16<3, false><<<512, 512, 0, stream>>>(ctx_bf, Wp_t, b_p, nullptr, out,
                                               nullptr, vproj_bf, pos_v, 8192, 1024, 1024);
  ln_kernel<<<8192, 256, 0, stream>>>(out, gamma, beta);
}

// Round 13
// 210.181 us; speedup vs baseline: 1.1622x; 1.1622x over previous
//
#include <hip/hip_runtime.h>

typedef unsigned short u16;
typedef unsigned int   u32;

using bf16x8 = __attribute__((ext_vector_type(8))) short;
using f32x4  = __attribute__((ext_vector_type(4))) float;

#define MFMA16(a, b, c) __builtin_amdgcn_mfma_f32_16x16x32_bf16((a), (b), (c), 0, 0, 0)

__device__ __forceinline__ u16 f2bf(float f) {
  union { float f; u32 u; } x; x.f = f;
  u32 r = x.u + 0x7fffu + ((x.u >> 16) & 1u);
  return (u16)(r >> 16);
}

__device__ __forceinline__ float bf2f(u16 v) {
  union { u32 u; float f; } x; x.u = ((u32)v) << 16;
  return x.f;
}

// packed f32x2 -> bf16x2 (RNE), single instruction; no builtin on gfx950
__device__ __forceinline__ u32 cvtpk(float lo, float hi) {
  u32 r;
  asm("v_cvt_pk_bf16_f32 %0, %1, %2" : "=v"(r) : "v"(lo), "v"(hi));
  return r;
}

// async global->LDS, 16B per lane; LDS dest must be wave-uniform base (HW adds lane*16)
__device__ __forceinline__ void gl2lds16(const void* g, void* l) {
  __builtin_amdgcn_global_load_lds(
      (const __attribute__((address_space(1))) u32*)g,
      (__attribute__((address_space(3))) u32*)l, 16, 0, 0);
}

// ---------------- merged fp32 -> bf16 elementwise (v and s in one launch) --
__global__ __launch_bounds__(256) void cvt_all(const float* __restrict__ v_in,
                                               u16* __restrict__ v_bf,
                                               const float* __restrict__ s_in,
                                               u16* __restrict__ s_bf) {
  long i = (long)blockIdx.x * 256 + threadIdx.x;
  const float* in;
  u16* out;
  if (i < 2097152) {            // v: 16.7M elems / 8
    in = v_in + i * 8;
    out = v_bf + i * 8;
  } else {                      // s: 6.3M elems / 8
    long j = i - 2097152;
    in = s_in + j * 8;
    out = s_bf + j * 8;
  }
  const float4* p = (const float4*)in;
  float4 a = p[0], b = p[1];
  uint4 pk;
  pk.x = cvtpk(a.x, a.y);
  pk.y = cvtpk(a.z, a.w);
  pk.z = cvtpk(b.x, b.y);
  pk.w = cvtpk(b.z, b.w);
  *(uint4*)out = pk;
}

// ---------------- weight convert + transpose body ---------------------------
__device__ __forceinline__ void wt_body(const float* __restrict__ W,
                                        u16* __restrict__ Wt, int K, int N,
                                        int bid, u16 (*t)[66]) {
  int tilesN = N >> 6;
  int k0 = (bid / tilesN) << 6;
  int n0 = (bid % tilesN) << 6;
  int tid = threadIdx.x;
  int c4 = (tid & 15) * 4, r16 = tid >> 4;
#pragma unroll
  for (int p = 0; p < 4; ++p) {
    int row = r16 + p * 16;
    float4 f = *(const float4*)(W + (size_t)(k0 + row) * N + n0 + c4);
    t[row][c4 + 0] = f2bf(f.x);
    t[row][c4 + 1] = f2bf(f.y);
    t[row][c4 + 2] = f2bf(f.z);
    t[row][c4 + 3] = f2bf(f.w);
  }
  __syncthreads();
  int c8 = (tid & 7) * 8, r32 = tid >> 3;
#pragma unroll
  for (int p = 0; p < 2; ++p) {
    int n = r32 + p * 32;
    u16 tmp[8] __attribute__((aligned(16)));
#pragma unroll
    for (int e = 0; e < 8; ++e) tmp[e] = t[c8 + e][n];
    *(uint4*)(Wt + (size_t)(n0 + n) * K + k0 + c8) = *(uint4*)tmp;
  }
}

// merged: all 5 weight transposes in one launch (block-range dispatch)
__global__ __launch_bounds__(256) void wt_all(
    const float* W_lv, u16* Wlv_t, const float* W_ls, u16* Wls_t,
    const float* W_q, u16* Wq_t, const float* W_v, u16* Wv_t,
    const float* W_p, u16* Wp_t) {
  __shared__ u16 t[64][66];
  int b = (int)blockIdx.x;
  if (b < 512)        wt_body(W_lv, Wlv_t, 2048, 1024, b, t);
  else if (b < 704)   wt_body(W_ls, Wls_t, 768, 1024, b - 512, t);
  else if (b < 960)   wt_body(W_q, Wq_t, 1024, 1024, b - 704, t);
  else if (b < 1216)  wt_body(W_v, Wv_t, 1024, 1024, b - 960, t);
  else                wt_body(W_p, Wp_t, 1024, 1024, b - 1216, t);
}

// ---------------- MFMA GEMM body (R6 core, verbatim) -----------------------
// 128x128 tile, BK=64, 8 waves (2m x 4n, 64x32/wave), XOR-swizzled LDS,
// double-buffered counted-vmcnt pipeline:
//   STAGE(kt+1) ; vmcnt(4) ; s_barrier ; COMPUTE(kt) ; s_barrier
// MODE 0: relu, write bf16
// MODE 2: write bf16 permuted to [B][H][L][64] (q-proj)
// MODE 4: like 2, plus transposed write [BH][64][512] (vs-proj)
// MODE 3: out = acc + bias + bf2f(add0b[m][n]) + add1[m&511][n], f32
struct GArgs {
  const u16* A; const u16* Bt; const float* bias;
  u16* outb; float* outf; u16* outt;
  const u16* add0b; const float* add1;
  int M, N, K;
};

template <int MODE>
__device__ __forceinline__ void gemm_body(u16* sAs, u16* sBs, const GArgs g,
                                          int orig, int nwg) {
  const u16* A = g.A;
  const u16* Bt = g.Bt;
  int N = g.N, K = g.K;
  int tilesN = N >> 7;
  // bijective XCD-chunked swizzle within this GEMM's block range
  int cpx = nwg >> 3;
  int wg = (orig & 7) * cpx + (orig >> 3);
  int tm = wg / tilesN, tn = wg % tilesN;
  int m0 = tm << 7, n0 = tn << 7;
  int tid = threadIdx.x, w = tid >> 6, l = tid & 63;
  int wm = (w >> 2) << 6, wn = (w & 3) << 5;
  int c16 = l & 15, hi = l >> 4, g16 = hi * 16;

  f32x4 acc[4][2];
#pragma unroll
  for (int i = 0; i < 4; ++i)
#pragma unroll
    for (int j = 0; j < 2; ++j) acc[i][j] = (f32x4){0.f, 0.f, 0.f, 0.f};

  auto STAGE = [&](int kt, int buf) {
    const u16* Ab = A + (size_t)m0 * K + kt * 64;
    const u16* Bb = Bt + (size_t)n0 * K + kt * 64;
#pragma unroll
    for (int p = 0; p < 2; ++p) {
      int lin = p * 8192 + tid * 16;            // linear byte in 16KB tile
      int row = lin >> 7;                       // 128B rows
      int cb = (lin & 127) ^ ((row & 7) << 4);  // pre-swizzled source column
      int base = lin & ~1023;                   // wave-uniform LDS chunk base
      gl2lds16(Ab + (size_t)row * K + (cb >> 1), (char*)sAs + buf * 16384 + base);
      gl2lds16(Bb + (size_t)row * K + (cb >> 1), (char*)sBs + buf * 16384 + base);
    }
  };

  auto COMPUTE = [&](int buf) {
#pragma unroll
    for (int kk = 0; kk < 2; ++kk) {
      bf16x8 af[4], bfr[2];
#pragma unroll
      for (int i = 0; i < 4; ++i) {
        int ar = wm + i * 16 + c16;
        af[i] = *(const bf16x8*)((const char*)sAs + buf * 16384 + ar * 128 +
                                 ((kk * 64 + g16) ^ ((ar & 7) << 4)));
      }
#pragma unroll
      for (int j = 0; j < 2; ++j) {
        int br = wn + j * 16 + c16;
        bfr[j] = *(const bf16x8*)((const char*)sBs + buf * 16384 + br * 128 +
                                  ((kk * 64 + g16) ^ ((br & 7) << 4)));
      }
#pragma unroll
      for (int i = 0; i < 4; ++i)
#pragma unroll
        for (int j = 0; j < 2; ++j) acc[i][j] = MFMA16(af[i], bfr[j], acc[i][j]);
    }
  };

  int nk = K >> 6;
  STAGE(0, 0);
  int cur = 0;
  for (int kt = 0; kt < nk; ++kt) {
    if (kt + 1 < nk) {
      STAGE(kt + 1, cur ^ 1);  // 4 more loads in flight (8 total)
      __builtin_amdgcn_sched_barrier(0);
      asm volatile("s_waitcnt vmcnt(4)" ::: "memory");  // tile kt landed
    } else {
      asm volatile("s_waitcnt vmcnt(0)" ::: "memory");  // final tile: full drain
    }
    __builtin_amdgcn_s_barrier();      // all waves: buf[cur] published
    __builtin_amdgcn_sched_barrier(0); // no ds_read hoisting above the barrier
    COMPUTE(cur);
    __builtin_amdgcn_sched_barrier(0);
    __builtin_amdgcn_s_barrier();      // all waves done reading before re-stage
    cur ^= 1;
  }

#pragma unroll
  for (int i = 0; i < 4; ++i) {
#pragma unroll
    for (int j = 0; j < 2; ++j) {
      float vv[4];
      int gn = n0 + wn + j * 16 + c16;
#pragma unroll
      for (int r = 0; r < 4; ++r) vv[r] = acc[i][j][r] + g.bias[gn];
      int gm0 = m0 + wm + i * 16 + hi * 4;
      if (MODE == 0) {
#pragma unroll
        for (int r = 0; r < 4; ++r)
          g.outb[(size_t)(gm0 + r) * N + gn] = f2bf(fmaxf(vv[r], 0.f));
      } else if (MODE == 2 || MODE == 4) {
        int hh = gn >> 6, dk = gn & 63, bb2 = gm0 >> 9, ll2 = gm0 & 511;
#pragma unroll
        for (int r = 0; r < 4; ++r)
          g.outb[(((size_t)bb2 * 16 + hh) * 512 + ll2 + r) * 64 + dk] = f2bf(vv[r]);
        if (MODE == 4) {
          uint2 tw;
          tw.x = cvtpk(vv[0], vv[1]);
          tw.y = cvtpk(vv[2], vv[3]);
          *(uint2*)(g.outt + (((size_t)bb2 * 16 + hh) * 64 + dk) * 512 + ll2) = tw;
        }
      } else {  // MODE 3
#pragma unroll
        for (int r = 0; r < 4; ++r) {
          int gm = gm0 + r;
          float v = vv[r] + bf2f(g.add0b[(size_t)gm * N + gn]) +
                    g.add1[(size_t)(gm & 511) * N + gn];
          g.outf[(size_t)gm * N + gn] = v;
        }
      }
    }
  }
}

// paired launch: blocks [0,512) run GEMM ga, [512,1024) run GEMM gb
template <int MODEA, int MODEB>
__global__ __launch_bounds__(512) void gemm_pair(GArgs ga, GArgs gb) {
  __shared__ u16 sA[2 * 8192];
  __shared__ u16 sB[2 * 8192];
  int b = (int)blockIdx.x;
  if (b < 512) gemm_body<MODEA>(sA, sB, ga, b, 512);
  else         gemm_body<MODEB>(sA, sB, gb, b - 512, 512);
}

template <int MODE>
__global__ __launch_bounds__(512) void gemm_single(GArgs g) {
  __shared__ u16 sA[2 * 8192];
  __shared__ u16 sB[2 * 8192];
  gemm_body<MODE>(sA, sB, g, (int)blockIdx.x, (int)gridDim.x);
}

// ---------------- fused attention: swapped-QK^T + swapped-PV ---------------
__global__ __launch_bounds__(512) void attn_kernel(const u16* __restrict__ q,
                                                   const u16* __restrict__ kv,
                                                   const u16* __restrict__ kvT,
                                                   u16* __restrict__ ctx) {
  __shared__ u16 sK[2][4096];   // [64 keys][64 dk], 128B rows, XOR swizzle
  __shared__ u16 sVT[2][4096];  // [64 dv][64 keys]
  __shared__ u16 sP[8192];      // Q staging (128x64), then per-wave P (16x64 each)

  int orig = (int)blockIdx.x;
  int r = (orig & 7) * 128 + (orig >> 3);
  int bh = r >> 2, qt = r & 3;
  int b = bh >> 4, h = bh & 15;
  int tid = threadIdx.x, w = tid >> 6, l = tid & 63;
  int c16 = l & 15, hi = l >> 4, g16 = hi * 16;
  int swzq = (c16 & 7) << 4;

  const u16* qbase = q + (size_t)bh * 32768 + (size_t)qt * 8192;
#pragma unroll
  for (int j = 0; j < 2; ++j) {
    int chunk = w * 2 + j;
    int lin = chunk * 1024 + l * 16;
    int row = lin >> 7;
    int cb = (lin & 127) ^ ((row & 7) << 4);
    gl2lds16(qbase + (size_t)row * 64 + (cb >> 1), (char*)sP + chunk * 1024);
  }
  {
    const u16* kb = kv + (size_t)bh * 32768;
    const u16* vb = kvT + (size_t)bh * 32768;
    int lin = w * 1024 + l * 16;
    int row = lin >> 7;
    int cb = (lin & 127) ^ ((row & 7) << 4);
    gl2lds16(kb + (size_t)row * 64 + (cb >> 1), (char*)sK[0] + w * 1024);
    gl2lds16(vb + (size_t)row * 512 + (cb >> 1), (char*)sVT[0] + w * 1024);
  }
  __syncthreads();

  const char* sQrow = (const char*)sP + (w * 16 + c16) * 128;
  bf16x8 qf0 = *(const bf16x8*)(sQrow + ((0 + g16) ^ swzq));
  bf16x8 qf1 = *(const bf16x8*)(sQrow + ((64 + g16) ^ swzq));

  char* sPw = (char*)sP + w * 2048;
  f32x4 of[4];
#pragma unroll
  for (int n = 0; n < 4; ++n) of[n] = (f32x4){0.f, 0.f, 0.f, 0.f};
  float m_run = -1e30f, l_run = 0.f;

  for (int c = 0; c < 8; ++c) {
    int cur = c & 1;
    if (c < 7) {
      const u16* kb = kv + (size_t)bh * 32768 + (size_t)(c + 1) * 4096;
      const u16* vb = kvT + (size_t)bh * 32768 + (c + 1) * 64;
      int lin = w * 1024 + l * 16;
      int row = lin >> 7;
      int cb = (lin & 127) ^ ((row & 7) << 4);
      gl2lds16(kb + (size_t)row * 64 + (cb >> 1), (char*)sK[cur ^ 1] + w * 1024);
      gl2lds16(vb + (size_t)row * 512 + (cb >> 1), (char*)sVT[cur ^ 1] + w * 1024);
    }
    const char* kbuf = (const char*)sK[cur];
    const char* vtbuf = (const char*)sVT[cur];

    f32x4 sf[4];
#pragma unroll
    for (int n = 0; n < 4; ++n) {
      const char* krow = kbuf + (n * 16 + c16) * 128;
      bf16x8 k0 = *(const bf16x8*)(krow + (g16 ^ swzq));
      bf16x8 k1 = *(const bf16x8*)(krow + ((64 + g16) ^ swzq));
      f32x4 z = (f32x4){0.f, 0.f, 0.f, 0.f};
      z = MFMA16(k0, qf0, z);
      z = MFMA16(k1, qf1, z);
      sf[n] = z;
    }

    float pmax = -1e30f;
#pragma unroll
    for (int n = 0; n < 4; ++n)
#pragma unroll
      for (int rr = 0; rr < 4; ++rr) {
        sf[n][rr] *= 0.125f;
        pmax = fmaxf(pmax, sf[n][rr]);
      }
    pmax = fmaxf(pmax, __shfl_xor(pmax, 16));
    pmax = fmaxf(pmax, __shfl_xor(pmax, 32));
    float mnew = fmaxf(m_run, pmax);
    float corr = __expf(m_run - mnew);
    float psum = 0.f;
#pragma unroll
    for (int n = 0; n < 4; ++n)
#pragma unroll
      for (int rr = 0; rr < 4; ++rr) {
        float p = __expf(sf[n][rr] - mnew);
        sf[n][rr] = p;
        psum += p;
      }
    psum += __shfl_xor(psum, 16);
    psum += __shfl_xor(psum, 32);
    l_run = l_run * corr + psum;
    m_run = mnew;
#pragma unroll
    for (int n = 0; n < 4; ++n)
#pragma unroll
      for (int rr = 0; rr < 4; ++rr) of[n][rr] *= corr;

#pragma unroll
    for (int n = 0; n < 4; ++n) {
      uint2 pw;
      pw.x = cvtpk(sf[n][0], sf[n][1]);
      pw.y = cvtpk(sf[n][2], sf[n][3]);
      *(uint2*)(sPw + c16 * 128 + ((n * 32 + hi * 8) ^ swzq)) = pw;
    }

    bf16x8 pf0 = *(const bf16x8*)(sPw + c16 * 128 + (g16 ^ swzq));
    bf16x8 pf1 = *(const bf16x8*)(sPw + c16 * 128 + ((64 + g16) ^ swzq));
#pragma unroll
    for (int n = 0; n < 4; ++n) {
      const char* vrow = vtbuf + (n * 16 + c16) * 128;
      bf16x8 v0 = *(const bf16x8*)(vrow + (g16 ^ swzq));
      bf16x8 v1 = *(const bf16x8*)(vrow + ((64 + g16) ^ swzq));
      of[n] = MFMA16(v0, pf0, of[n]);
      of[n] = MFMA16(v1, pf1, of[n]);
    }
    __syncthreads();
  }

  float inv = 1.0f / l_run;
  int grow = qt * 128 + w * 16 + c16;
  u16* obase = ctx + (size_t)(b * 512 + grow) * 1024 + h * 64;
#pragma unroll
  for (int n = 0; n < 4; ++n) {
    uint2 ow;
    ow.x = cvtpk(of[n][0] * inv, of[n][1] * inv);
    ow.y = cvtpk(of[n][2] * inv, of[n][3] * inv);
    *(uint2*)(obase + n * 16 + hi * 4) = ow;
  }
}

// ---------------- in-place LayerNorm over D=1024 ---------------------------
__global__ __launch_bounds__(256) void ln_kernel(float* __restrict__ x,
                                                 const float* __restrict__ gamma,
                                                 const float* __restrict__ beta) {
  __shared__ float red[4];
  __shared__ float red2[4];
  int row = blockIdx.x, tid = threadIdx.x;
  float4 v = *(float4*)(x + (size_t)row * 1024 + tid * 4);
  float s = v.x + v.y + v.z + v.w;
#pragma unroll
  for (int d = 1; d < 64; d <<= 1) s += __shfl_xor(s, d);
  if ((tid & 63) == 0) red[tid >> 6] = s;
  __syncthreads();
  float mu = (red[0] + red[1] + red[2] + red[3]) * (1.0f / 1024.0f);
  float d0 = v.x - mu, d1 = v.y - mu, d2 = v.z - mu, d3 = v.w - mu;
  float qq = d0 * d0 + d1 * d1 + d2 * d2 + d3 * d3;
#pragma unroll
  for (int d = 1; d < 64; d <<= 1) qq += __shfl_xor(qq, d);
  if ((tid & 63) == 0) red2[tid >> 6] = qq;
  __syncthreads();
  float var = (red2[0] + red2[1] + red2[2] + red2[3]) * (1.0f / 1024.0f);
  float rstd = rsqrtf(var + 1e-6f);
  float4 g = *(const float4*)(gamma + tid * 4);
  float4 bb = *(const float4*)(beta + tid * 4);
  v.x = g.x * d0 * rstd + bb.x;
  v.y = g.y * d1 * rstd + bb.y;
  v.z = g.z * d2 * rstd + bb.z;
  v.w = g.w * d3 * rstd + bb.w;
  *(float4*)(x + (size_t)row * 1024 + tid * 4) = v;
}

extern "C" void kernel_launch(void* const* d_in, const int* in_sizes, int n_in,
                              void* d_out, int out_size, void* d_ws, size_t ws_size,
                              hipStream_t stream) {
  (void)in_sizes; (void)n_in; (void)out_size; (void)ws_size;
  const float* v_in  = (const float*)d_in[0];
  const float* s_in  = (const float*)d_in[1];
  const float* W_lv  = (const float*)d_in[2];
  const float* b_lv  = (const float*)d_in[3];
  const float* W_ls  = (const float*)d_in[4];
  const float* b_ls  = (const float*)d_in[5];
  const float* pos_v = (const float*)d_in[6];
  // d_in[7] = pos_s (unused), d_in[10]/[11] = W_k/b_k (discarded in ref)
  const float* W_q   = (const float*)d_in[8];
  const float* b_q   = (const float*)d_in[9];
  const float* W_v   = (const float*)d_in[12];
  const float* b_v   = (const float*)d_in[13];
  const float* W_p   = (const float*)d_in[14];
  const float* b_p   = (const float*)d_in[15];
  const float* gamma = (const float*)d_in[16];
  const float* beta  = (const float*)d_in[17];
  float* out = (float*)d_out;

  char* ws = (char*)d_ws;
  size_t off = 0;
  auto alloc = [&](size_t bytes) {
    char* p = ws + off;
    off += (bytes + 255) & ~(size_t)255;
    return p;
  };
  u16* v_bf     = (u16*)alloc(33554432);   // [8192][2048] bf16
  u16* s_bf     = (u16*)alloc(12582912);   // [8192][768]
  u16* Wlv_t    = (u16*)alloc(4194304);    // [1024][2048] bf16
  u16* Wls_t    = (u16*)alloc(1572864);    // [1024][768]
  u16* Wq_t     = (u16*)alloc(2097152);    // [1024][1024]
  u16* Wv_t     = (u16*)alloc(2097152);
  u16* Wp_t     = (u16*)alloc(2097152);
  u16* vproj_bf = (u16*)alloc(16777216);   // [8192][1024] (also the residual, bf16)
  u16* sproj_bf = (u16*)alloc(16777216);
  u16* q_bf     = (u16*)alloc(16777216);   // [BH][512][64]
  u16* vs_bf    = (u16*)alloc(16777216);   // [BH][512][64]
  u16* vsT_bf   = (u16*)alloc(16777216);   // [BH][64][512]
  u16* ctx_bf   = (u16*)alloc(16777216);   // [8192][1024]

  // merged conversion + weight transposes (7 dispatches total this launch)
  cvt_all<<<11264, 256, 0, stream>>>(v_in, v_bf, s_in, s_bf);
  wt_all<<<1472, 256, 0, stream>>>(W_lv, Wlv_t, W_ls, Wls_t, W_q, Wq_t,
                                   W_v, Wv_t, W_p, Wp_t);

  GArgs av  = {v_bf, Wlv_t, b_lv, vproj_bf, nullptr, nullptr, nullptr, nullptr,
               8192, 1024, 2048};
  GArgs as  = {s_bf, Wls_t, b_ls, sproj_bf, nullptr, nullptr, nullptr, nullptr,
               8192, 1024, 768};
  GArgs aq  = {vproj_bf, Wq_t, b_q, q_bf, nullptr, nullptr, nullptr, nullptr,
               8192, 1024, 1024};
  GArgs avs = {sproj_bf, Wv_t, b_v, vs_bf, nullptr, vsT_bf, nullptr, nullptr,
               8192, 1024, 1024};
  GArgs ao  = {ctx_bf, Wp_t, b_p, nullptr, out, nullptr, vproj_bf, pos_v,
               8192, 1024, 1024};

  // v-proj (K=2048) || s-proj (K=768) in one dispatch
  gemm_pair<0, 0><<<1024, 512, 0, stream>>>(av, as);
  // q-proj || vs-proj(+transpose) in one dispatch
  gemm_pair<2, 4><<<1024, 512, 0, stream>>>(aq, avs);
  attn_kernel<<<1024, 512, 0, stream>>>(q_bf, vs_bf, vsT_bf, ctx_bf);
  // out-proj + residual(bf16) + pos_v
  gemm_single<3><<<512, 512, 0, stream>>>(ao);
  ln_kernel<<<8192, 256, 0, stream>>>(out, gamma, beta);
}

// Round 14
// 198.712 us; speedup vs baseline: 1.2292x; 1.0577x over previous
//
#include <hip/hip_runtime.h>

typedef unsigned short u16;
typedef unsigned int   u32;

using bf16x8 = __attribute__((ext_vector_type(8))) short;
using f32x4  = __attribute__((ext_vector_type(4))) float;

#define MFMA16(a, b, c) __builtin_amdgcn_mfma_f32_16x16x32_bf16((a), (b), (c), 0, 0, 0)

__device__ __forceinline__ u16 f2bf(float f) {
  union { float f; u32 u; } x; x.f = f;
  u32 r = x.u + 0x7fffu + ((x.u >> 16) & 1u);
  return (u16)(r >> 16);
}

__device__ __forceinline__ float bf2f(u16 v) {
  union { u32 u; float f; } x; x.u = ((u32)v) << 16;
  return x.f;
}

// packed f32x2 -> bf16x2 (RNE), single instruction; no builtin on gfx950
__device__ __forceinline__ u32 cvtpk(float lo, float hi) {
  u32 r;
  asm("v_cvt_pk_bf16_f32 %0, %1, %2" : "=v"(r) : "v"(lo), "v"(hi));
  return r;
}

// async global->LDS, 16B per lane; LDS dest must be wave-uniform base (HW adds lane*16)
__device__ __forceinline__ void gl2lds16(const void* g, void* l) {
  __builtin_amdgcn_global_load_lds(
      (const __attribute__((address_space(1))) u32*)g,
      (__attribute__((address_space(3))) u32*)l, 16, 0, 0);
}

// ---------------- weight convert + transpose body ---------------------------
__device__ __forceinline__ void wt_body(const float* __restrict__ W,
                                        u16* __restrict__ Wt, int K, int N,
                                        int bid, u16 (*t)[66]) {
  int tilesN = N >> 6;
  int k0 = (bid / tilesN) << 6;
  int n0 = (bid % tilesN) << 6;
  int tid = threadIdx.x;
  int c4 = (tid & 15) * 4, r16 = tid >> 4;
#pragma unroll
  for (int p = 0; p < 4; ++p) {
    int row = r16 + p * 16;
    float4 f = *(const float4*)(W + (size_t)(k0 + row) * N + n0 + c4);
    t[row][c4 + 0] = f2bf(f.x);
    t[row][c4 + 1] = f2bf(f.y);
    t[row][c4 + 2] = f2bf(f.z);
    t[row][c4 + 3] = f2bf(f.w);
  }
  __syncthreads();
  int c8 = (tid & 7) * 8, r32 = tid >> 3;
#pragma unroll
  for (int p = 0; p < 2; ++p) {
    int n = r32 + p * 32;
    u16 tmp[8] __attribute__((aligned(16)));
#pragma unroll
    for (int e = 0; e < 8; ++e) tmp[e] = t[c8 + e][n];
    *(uint4*)(Wt + (size_t)(n0 + n) * K + k0 + c8) = *(uint4*)tmp;
  }
}

// ---------------- merged prologue: activation cvt + all weight transposes --
__global__ __launch_bounds__(256) void prologue_all(
    const float* v_in, u16* v_bf, const float* s_in, u16* s_bf,
    const float* W_lv, u16* Wlv_t, const float* W_ls, u16* Wls_t,
    const float* W_q, u16* Wq_t, const float* W_v, u16* Wv_t,
    const float* W_p, u16* Wp_t) {
  __shared__ u16 t[64][66];
  long blk = (long)blockIdx.x;
  if (blk < 11264) {  // activation cvt: v (8192 blocks) then s (3072)
    long i = blk * 256 + threadIdx.x;
    const float* in;
    u16* out;
    if (i < 2097152) {
      in = v_in + i * 8;
      out = v_bf + i * 8;
    } else {
      long j = i - 2097152;
      in = s_in + j * 8;
      out = s_bf + j * 8;
    }
    const float4* p = (const float4*)in;
    float4 a = p[0], b = p[1];
    uint4 pk;
    pk.x = cvtpk(a.x, a.y);
    pk.y = cvtpk(a.z, a.w);
    pk.z = cvtpk(b.x, b.y);
    pk.w = cvtpk(b.z, b.w);
    *(uint4*)out = pk;
  } else {
    int b = (int)blk - 11264;
    if (b < 512)        wt_body(W_lv, Wlv_t, 2048, 1024, b, t);
    else if (b < 704)   wt_body(W_ls, Wls_t, 768, 1024, b - 512, t);
    else if (b < 960)   wt_body(W_q, Wq_t, 1024, 1024, b - 704, t);
    else if (b < 1216)  wt_body(W_v, Wv_t, 1024, 1024, b - 960, t);
    else                wt_body(W_p, Wp_t, 1024, 1024, b - 1216, t);
  }
}

// ---------------- MFMA GEMM body (R6 core) ---------------------------------
// 128x128 tile, BK=64, 8 waves (2m x 4n, 64x32/wave), XOR-swizzled LDS,
// double-buffered counted-vmcnt pipeline:
//   STAGE(kt+1) ; vmcnt(4) ; s_barrier ; COMPUTE(kt) ; s_barrier
// MODE 0: relu, write bf16
// MODE 2: write bf16*0.125 permuted to [B][H][L][64] (q-proj, scale folded)
// MODE 4: write bf16 permuted + transposed [BH][64][512] (vs-proj)
// MODE 5: plain bf16 write (out-proj raw; residual/pos/LN fused downstream)
struct GArgs {
  const u16* A; const u16* Bt; const float* bias;
  u16* outb; float* outf; u16* outt;
  const u16* add0b; const float* add1;
  int M, N, K;
};

template <int MODE>
__device__ __forceinline__ void gemm_body(u16* sAs, u16* sBs, const GArgs g,
                                          int orig, int nwg) {
  const u16* A = g.A;
  const u16* Bt = g.Bt;
  int N = g.N, K = g.K;
  int tilesN = N >> 7;
  // bijective XCD-chunked swizzle within this GEMM's block range
  int cpx = nwg >> 3;
  int wg = (orig & 7) * cpx + (orig >> 3);
  int tm = wg / tilesN, tn = wg % tilesN;
  int m0 = tm << 7, n0 = tn << 7;
  int tid = threadIdx.x, w = tid >> 6, l = tid & 63;
  int wm = (w >> 2) << 6, wn = (w & 3) << 5;
  int c16 = l & 15, hi = l >> 4, g16 = hi * 16;

  f32x4 acc[4][2];
#pragma unroll
  for (int i = 0; i < 4; ++i)
#pragma unroll
    for (int j = 0; j < 2; ++j) acc[i][j] = (f32x4){0.f, 0.f, 0.f, 0.f};

  auto STAGE = [&](int kt, int buf) {
    const u16* Ab = A + (size_t)m0 * K + kt * 64;
    const u16* Bb = Bt + (size_t)n0 * K + kt * 64;
#pragma unroll
    for (int p = 0; p < 2; ++p) {
      int lin = p * 8192 + tid * 16;            // linear byte in 16KB tile
      int row = lin >> 7;                       // 128B rows
      int cb = (lin & 127) ^ ((row & 7) << 4);  // pre-swizzled source column
      int base = lin & ~1023;                   // wave-uniform LDS chunk base
      gl2lds16(Ab + (size_t)row * K + (cb >> 1), (char*)sAs + buf * 16384 + base);
      gl2lds16(Bb + (size_t)row * K + (cb >> 1), (char*)sBs + buf * 16384 + base);
    }
  };

  auto COMPUTE = [&](int buf) {
#pragma unroll
    for (int kk = 0; kk < 2; ++kk) {
      bf16x8 af[4], bfr[2];
#pragma unroll
      for (int i = 0; i < 4; ++i) {
        int ar = wm + i * 16 + c16;
        af[i] = *(const bf16x8*)((const char*)sAs + buf * 16384 + ar * 128 +
                                 ((kk * 64 + g16) ^ ((ar & 7) << 4)));
      }
#pragma unroll
      for (int j = 0; j < 2; ++j) {
        int br = wn + j * 16 + c16;
        bfr[j] = *(const bf16x8*)((const char*)sBs + buf * 16384 + br * 128 +
                                  ((kk * 64 + g16) ^ ((br & 7) << 4)));
      }
#pragma unroll
      for (int i = 0; i < 4; ++i)
#pragma unroll
        for (int j = 0; j < 2; ++j) acc[i][j] = MFMA16(af[i], bfr[j], acc[i][j]);
    }
  };

  int nk = K >> 6;
  STAGE(0, 0);
  int cur = 0;
  for (int kt = 0; kt < nk; ++kt) {
    if (kt + 1 < nk) {
      STAGE(kt + 1, cur ^ 1);  // 4 more loads in flight (8 total)
      __builtin_amdgcn_sched_barrier(0);
      asm volatile("s_waitcnt vmcnt(4)" ::: "memory");  // tile kt landed
    } else {
      asm volatile("s_waitcnt vmcnt(0)" ::: "memory");  // final tile: full drain
    }
    __builtin_amdgcn_s_barrier();      // all waves: buf[cur] published
    __builtin_amdgcn_sched_barrier(0); // no ds_read hoisting above the barrier
    COMPUTE(cur);
    __builtin_amdgcn_sched_barrier(0);
    __builtin_amdgcn_s_barrier();      // all waves done reading before re-stage
    cur ^= 1;
  }

#pragma unroll
  for (int i = 0; i < 4; ++i) {
#pragma unroll
    for (int j = 0; j < 2; ++j) {
      float vv[4];
      int gn = n0 + wn + j * 16 + c16;
#pragma unroll
      for (int r = 0; r < 4; ++r) vv[r] = acc[i][j][r] + g.bias[gn];
      int gm0 = m0 + wm + i * 16 + hi * 4;
      if (MODE == 0) {
#pragma unroll
        for (int r = 0; r < 4; ++r)
          g.outb[(size_t)(gm0 + r) * N + gn] = f2bf(fmaxf(vv[r], 0.f));
      } else if (MODE == 5) {
#pragma unroll
        for (int r = 0; r < 4; ++r)
          g.outb[(size_t)(gm0 + r) * N + gn] = f2bf(vv[r]);
      } else if (MODE == 2 || MODE == 4) {
        int hh = gn >> 6, dk = gn & 63, bb2 = gm0 >> 9, ll2 = gm0 & 511;
#pragma unroll
        for (int r = 0; r < 4; ++r) {
          float ov = (MODE == 2) ? vv[r] * 0.125f : vv[r];  // q: fold 1/sqrt(DK)
          g.outb[(((size_t)bb2 * 16 + hh) * 512 + ll2 + r) * 64 + dk] = f2bf(ov);
        }
        if (MODE == 4) {
          uint2 tw;
          tw.x = cvtpk(vv[0], vv[1]);
          tw.y = cvtpk(vv[2], vv[3]);
          *(uint2*)(g.outt + (((size_t)bb2 * 16 + hh) * 64 + dk) * 512 + ll2) = tw;
        }
      }
    }
  }
}

// paired launch: blocks [0,512) run GEMM ga, [512,1024) run GEMM gb
template <int MODEA, int MODEB>
__global__ __launch_bounds__(512) void gemm_pair(GArgs ga, GArgs gb) {
  __shared__ u16 sA[2 * 8192];
  __shared__ u16 sB[2 * 8192];
  int b = (int)blockIdx.x;
  if (b < 512) gemm_body<MODEA>(sA, sB, ga, b, 512);
  else         gemm_body<MODEB>(sA, sB, gb, b - 512, 512);
}

template <int MODE>
__global__ __launch_bounds__(512) void gemm_single(GArgs g) {
  __shared__ u16 sA[2 * 8192];
  __shared__ u16 sB[2 * 8192];
  gemm_body<MODE>(sA, sB, g, (int)blockIdx.x, (int)gridDim.x);
}

// ---------------- fused attention: swapped-QK^T + swapped-PV + defer-max ---
__global__ __launch_bounds__(512) void attn_kernel(const u16* __restrict__ q,
                                                   const u16* __restrict__ kv,
                                                   const u16* __restrict__ kvT,
                                                   u16* __restrict__ ctx) {
  __shared__ u16 sK[2][4096];   // [64 keys][64 dk], 128B rows, XOR swizzle
  __shared__ u16 sVT[2][4096];  // [64 dv][64 keys]
  __shared__ u16 sP[8192];      // Q staging (128x64), then per-wave P (16x64 each)

  int orig = (int)blockIdx.x;
  int r = (orig & 7) * 128 + (orig >> 3);
  int bh = r >> 2, qt = r & 3;
  int b = bh >> 4, h = bh & 15;
  int tid = threadIdx.x, w = tid >> 6, l = tid & 63;
  int c16 = l & 15, hi = l >> 4, g16 = hi * 16;
  int swzq = (c16 & 7) << 4;

  const u16* qbase = q + (size_t)bh * 32768 + (size_t)qt * 8192;
#pragma unroll
  for (int j = 0; j < 2; ++j) {
    int chunk = w * 2 + j;
    int lin = chunk * 1024 + l * 16;
    int row = lin >> 7;
    int cb = (lin & 127) ^ ((row & 7) << 4);
    gl2lds16(qbase + (size_t)row * 64 + (cb >> 1), (char*)sP + chunk * 1024);
  }
  {
    const u16* kb = kv + (size_t)bh * 32768;
    const u16* vb = kvT + (size_t)bh * 32768;
    int lin = w * 1024 + l * 16;
    int row = lin >> 7;
    int cb = (lin & 127) ^ ((row & 7) << 4);
    gl2lds16(kb + (size_t)row * 64 + (cb >> 1), (char*)sK[0] + w * 1024);
    gl2lds16(vb + (size_t)row * 512 + (cb >> 1), (char*)sVT[0] + w * 1024);
  }
  __syncthreads();

  const char* sQrow = (const char*)sP + (w * 16 + c16) * 128;
  bf16x8 qf0 = *(const bf16x8*)(sQrow + ((0 + g16) ^ swzq));
  bf16x8 qf1 = *(const bf16x8*)(sQrow + ((64 + g16) ^ swzq));

  char* sPw = (char*)sP + w * 2048;
  f32x4 of[4];
#pragma unroll
  for (int n = 0; n < 4; ++n) of[n] = (f32x4){0.f, 0.f, 0.f, 0.f};
  float m_run = -1e30f, l_run = 0.f;

  for (int c = 0; c < 8; ++c) {
    int cur = c & 1;
    if (c < 7) {
      const u16* kb = kv + (size_t)bh * 32768 + (size_t)(c + 1) * 4096;
      const u16* vb = kvT + (size_t)bh * 32768 + (c + 1) * 64;
      int lin = w * 1024 + l * 16;
      int row = lin >> 7;
      int cb = (lin & 127) ^ ((row & 7) << 4);
      gl2lds16(kb + (size_t)row * 64 + (cb >> 1), (char*)sK[cur ^ 1] + w * 1024);
      gl2lds16(vb + (size_t)row * 512 + (cb >> 1), (char*)sVT[cur ^ 1] + w * 1024);
    }
    const char* kbuf = (const char*)sK[cur];
    const char* vtbuf = (const char*)sVT[cur];

    // S^T = K * Q  (Q pre-scaled by 0.125 in the q-proj epilogue)
    f32x4 sf[4];
#pragma unroll
    for (int n = 0; n < 4; ++n) {
      const char* krow = kbuf + (n * 16 + c16) * 128;
      bf16x8 k0 = *(const bf16x8*)(krow + (g16 ^ swzq));
      bf16x8 k1 = *(const bf16x8*)(krow + ((64 + g16) ^ swzq));
      f32x4 z = (f32x4){0.f, 0.f, 0.f, 0.f};
      z = MFMA16(k0, qf0, z);
      z = MFMA16(k1, qf1, z);
      sf[n] = z;
    }

    float pmax = -1e30f;
#pragma unroll
    for (int n = 0; n < 4; ++n)
#pragma unroll
      for (int rr = 0; rr < 4; ++rr) pmax = fmaxf(pmax, sf[n][rr]);
    pmax = fmaxf(pmax, __shfl_xor(pmax, 16));
    pmax = fmaxf(pmax, __shfl_xor(pmax, 32));

    // T13 defer-max: skip O-rescale while max growth <= 8 (wave-uniform)
    bool defer = __all(pmax - m_run <= 8.f) != 0;
    float mnew = defer ? m_run : fmaxf(m_run, pmax);
    if (!defer) {
      float corr = __expf(m_run - mnew);
#pragma unroll
      for (int n = 0; n < 4; ++n)
#pragma unroll
        for (int rr = 0; rr < 4; ++rr) of[n][rr] *= corr;
      l_run *= corr;
      m_run = mnew;
    }
    float psum = 0.f;
#pragma unroll
    for (int n = 0; n < 4; ++n)
#pragma unroll
      for (int rr = 0; rr < 4; ++rr) {
        float p = __expf(sf[n][rr] - m_run);
        sf[n][rr] = p;
        psum += p;
      }
    psum += __shfl_xor(psum, 16);
    psum += __shfl_xor(psum, 32);
    l_run += psum;

#pragma unroll
    for (int n = 0; n < 4; ++n) {
      uint2 pw;
      pw.x = cvtpk(sf[n][0], sf[n][1]);
      pw.y = cvtpk(sf[n][2], sf[n][3]);
      *(uint2*)(sPw + c16 * 128 + ((n * 32 + hi * 8) ^ swzq)) = pw;
    }

    bf16x8 pf0 = *(const bf16x8*)(sPw + c16 * 128 + (g16 ^ swzq));
    bf16x8 pf1 = *(const bf16x8*)(sPw + c16 * 128 + ((64 + g16) ^ swzq));
#pragma unroll
    for (int n = 0; n < 4; ++n) {
      const char* vrow = vtbuf + (n * 16 + c16) * 128;
      bf16x8 v0 = *(const bf16x8*)(vrow + (g16 ^ swzq));
      bf16x8 v1 = *(const bf16x8*)(vrow + ((64 + g16) ^ swzq));
      of[n] = MFMA16(v0, pf0, of[n]);
      of[n] = MFMA16(v1, pf1, of[n]);
    }
    __syncthreads();
  }

  float inv = 1.0f / l_run;
  int grow = qt * 128 + w * 16 + c16;
  u16* obase = ctx + (size_t)(b * 512 + grow) * 1024 + h * 64;
#pragma unroll
  for (int n = 0; n < 4; ++n) {
    uint2 ow;
    ow.x = cvtpk(of[n][0] * inv, of[n][1] * inv);
    ow.y = cvtpk(of[n][2] * inv, of[n][3] * inv);
    *(uint2*)(obase + n * 16 + hi * 4) = ow;
  }
}

// ---------------- fused LayerNorm: x = gemm_bf + resid_bf + pos; LN -> f32 --
__global__ __launch_bounds__(256) void ln_fused(const u16* __restrict__ gbf,
                                                const u16* __restrict__ resid,
                                                const float* __restrict__ pos,
                                                const float* __restrict__ gamma,
                                                const float* __restrict__ beta,
                                                float* __restrict__ out) {
  __shared__ float red[4];
  __shared__ float red2[4];
  int row = blockIdx.x, tid = threadIdx.x;
  size_t base = (size_t)row * 1024 + tid * 4;
  uint2 gg = *(const uint2*)(gbf + base);
  uint2 rr = *(const uint2*)(resid + base);
  float4 pp = *(const float4*)(pos + (size_t)(row & 511) * 1024 + tid * 4);
  float x0 = bf2f((u16)(gg.x & 0xffff)) + bf2f((u16)(rr.x & 0xffff)) + pp.x;
  float x1 = bf2f((u16)(gg.x >> 16))    + bf2f((u16)(rr.x >> 16))    + pp.y;
  float x2 = bf2f((u16)(gg.y & 0xffff)) + bf2f((u16)(rr.y & 0xffff)) + pp.z;
  float x3 = bf2f((u16)(gg.y >> 16))    + bf2f((u16)(rr.y >> 16))    + pp.w;
  float s = x0 + x1 + x2 + x3;
#pragma unroll
  for (int d = 1; d < 64; d <<= 1) s += __shfl_xor(s, d);
  if ((tid & 63) == 0) red[tid >> 6] = s;
  __syncthreads();
  float mu = (red[0] + red[1] + red[2] + red[3]) * (1.0f / 1024.0f);
  float d0 = x0 - mu, d1 = x1 - mu, d2 = x2 - mu, d3 = x3 - mu;
  float qq = d0 * d0 + d1 * d1 + d2 * d2 + d3 * d3;
#pragma unroll
  for (int d = 1; d < 64; d <<= 1) qq += __shfl_xor(qq, d);
  if ((tid & 63) == 0) red2[tid >> 6] = qq;
  __syncthreads();
  float var = (red2[0] + red2[1] + red2[2] + red2[3]) * (1.0f / 1024.0f);
  float rstd = rsqrtf(var + 1e-6f);
  float4 g4 = *(const float4*)(gamma + tid * 4);
  float4 b4 = *(const float4*)(beta + tid * 4);
  float4 o;
  o.x = g4.x * d0 * rstd + b4.x;
  o.y = g4.y * d1 * rstd + b4.y;
  o.z = g4.z * d2 * rstd + b4.z;
  o.w = g4.w * d3 * rstd + b4.w;
  *(float4*)(out + base) = o;
}

extern "C" void kernel_launch(void* const* d_in, const int* in_sizes, int n_in,
                              void* d_out, int out_size, void* d_ws, size_t ws_size,
                              hipStream_t stream) {
  (void)in_sizes; (void)n_in; (void)out_size; (void)ws_size;
  const float* v_in  = (const float*)d_in[0];
  const float* s_in  = (const float*)d_in[1];
  const float* W_lv  = (const float*)d_in[2];
  const float* b_lv  = (const float*)d_in[3];
  const float* W_ls  = (const float*)d_in[4];
  const float* b_ls  = (const float*)d_in[5];
  const float* pos_v = (const float*)d_in[6];
  // d_in[7] = pos_s (unused), d_in[10]/[11] = W_k/b_k (discarded in ref)
  const float* W_q   = (const float*)d_in[8];
  const float* b_q   = (const float*)d_in[9];
  const float* W_v   = (const float*)d_in[12];
  const float* b_v   = (const float*)d_in[13];
  const float* W_p   = (const float*)d_in[14];
  const float* b_p   = (const float*)d_in[15];
  const float* gamma = (const float*)d_in[16];
  const float* beta  = (const float*)d_in[17];
  float* out = (float*)d_out;

  char* ws = (char*)d_ws;
  size_t off = 0;
  auto alloc = [&](size_t bytes) {
    char* p = ws + off;
    off += (bytes + 255) & ~(size_t)255;
    return p;
  };
  u16* v_bf     = (u16*)alloc(33554432);   // [8192][2048] bf16
  u16* s_bf     = (u16*)alloc(12582912);   // [8192][768]
  u16* Wlv_t    = (u16*)alloc(4194304);    // [1024][2048] bf16
  u16* Wls_t    = (u16*)alloc(1572864);    // [1024][768]
  u16* Wq_t     = (u16*)alloc(2097152);    // [1024][1024]
  u16* Wv_t     = (u16*)alloc(2097152);
  u16* Wp_t     = (u16*)alloc(2097152);
  u16* vproj_bf = (u16*)alloc(16777216);   // [8192][1024] (also the residual, bf16)
  u16* sproj_bf = (u16*)alloc(16777216);
  u16* q_bf     = (u16*)alloc(16777216);   // [BH][512][64]
  u16* vs_bf    = (u16*)alloc(16777216);   // [BH][512][64]
  u16* vsT_bf   = (u16*)alloc(16777216);   // [BH][64][512]
  u16* ctx_bf   = (u16*)alloc(16777216);   // [8192][1024]
  u16* oproj_bf = (u16*)alloc(16777216);   // [8192][1024] raw out-proj result

  // merged prologue: both activation cvts + all 5 weight transposes
  prologue_all<<<12736, 256, 0, stream>>>(v_in, v_bf, s_in, s_bf,
                                          W_lv, Wlv_t, W_ls, Wls_t, W_q, Wq_t,
                                          W_v, Wv_t, W_p, Wp_t);

  GArgs av  = {v_bf, Wlv_t, b_lv, vproj_bf, nullptr, nullptr, nullptr, nullptr,
               8192, 1024, 2048};
  GArgs as  = {s_bf, Wls_t, b_ls, sproj_bf, nullptr, nullptr, nullptr, nullptr,
               8192, 1024, 768};
  GArgs aq  = {vproj_bf, Wq_t, b_q, q_bf, nullptr, nullptr, nullptr, nullptr,
               8192, 1024, 1024};
  GArgs avs = {sproj_bf, Wv_t, b_v, vs_bf, nullptr, vsT_bf, nullptr, nullptr,
               8192, 1024, 1024};
  GArgs ao  = {ctx_bf, Wp_t, b_p, oproj_bf, nullptr, nullptr, nullptr, nullptr,
               8192, 1024, 1024};

  // v-proj (K=2048) || s-proj (K=768) in one dispatch
  gemm_pair<0, 0><<<1024, 512, 0, stream>>>(av, as);
  // q-proj (scale folded) || vs-proj(+transpose) in one dispatch
  gemm_pair<2, 4><<<1024, 512, 0, stream>>>(aq, avs);
  attn_kernel<<<1024, 512, 0, stream>>>(q_bf, vs_bf, vsT_bf, ctx_bf);
  // out-proj raw bf16 (residual/pos/LN fused into ln_fused)
  gemm_single<5><<<512, 512, 0, stream>>>(ao);
  ln_fused<<<8192, 256, 0, stream>>>(oproj_bf, vproj_bf, pos_v, gamma, beta, out);
}